// Round 1
// baseline (216.671 us; speedup 1.0000x reference)
//
#include <hip/hip_runtime.h>

#define N_B    8
#define L_SEQ  2040
#define D_DIM  768
#define KDIM   2304      // 3*768
#define M_ROWS 16320     // N_B*L_SEQ
#define LPAD   2042      // L_SEQ + 2 zero guard rows

typedef __bf16 bf16x8 __attribute__((ext_vector_type(8)));
typedef float  f32x4  __attribute__((ext_vector_type(4)));

__device__ __forceinline__ unsigned short f2bf_u(float f) {
  union { float f; unsigned u; } v; v.f = f;
  unsigned u = v.u;
  return (unsigned short)((u + 0x7FFFu + ((u >> 16) & 1u)) >> 16);
}

__device__ __forceinline__ void async16(const unsigned short* g, unsigned short* l) {
  __builtin_amdgcn_global_load_lds(
      (const __attribute__((address_space(1))) void*)g,
      (__attribute__((address_space(3))) void*)l, 16, 0, 0);
}

// ---------------- P0: pad + fp32->bf16 convert X ----------------
// Xpad[n][lp][d]: lp=0 and lp=LPAD-1 are zero rows, lp=1..L_SEQ map to l=0..L_SEQ-1
__global__ void k_pad(const float* __restrict__ X, unsigned short* __restrict__ Xpad) {
  size_t idx = ((size_t)blockIdx.x * 256 + threadIdx.x) * 4;
  const size_t per_n = (size_t)LPAD * D_DIM;
  if (idx >= (size_t)N_B * per_n) return;
  int n = (int)(idx / per_n);
  size_t rem = idx - (size_t)n * per_n;
  int lp = (int)(rem / D_DIM);
  int d  = (int)(rem - (size_t)lp * D_DIM);
  ushort4 o;
  if (lp == 0 || lp == LPAD - 1) {
    o.x = 0; o.y = 0; o.z = 0; o.w = 0;
  } else {
    const float4 f = *(const float4*)&X[((size_t)n * L_SEQ + (lp - 1)) * D_DIM + d];
    o.x = f2bf_u(f.x); o.y = f2bf_u(f.y); o.z = f2bf_u(f.z); o.w = f2bf_u(f.w);
  }
  *(ushort4*)&Xpad[idx] = o;
}

// ---------------- P1: fp32 [R][C] -> bf16 transposed [C][R] ----------------
__global__ void k_transpose(const float* __restrict__ in, unsigned short* __restrict__ out,
                            int R, int C) {
  __shared__ float tile[32][33];
  int tx = threadIdx.x, ty = threadIdx.y;
  int c0 = blockIdx.x * 32;
  int r0 = blockIdx.y * 32;
  for (int i = ty; i < 32; i += 8) {
    int r = r0 + i, c = c0 + tx;
    tile[i][tx] = (r < R && c < C) ? in[(size_t)r * C + c] : 0.f;
  }
  __syncthreads();
  for (int i = ty; i < 32; i += 8) {
    int oc = c0 + i;    // output row  = original col
    int orr = r0 + tx;  // output col  = original row
    if (oc < C && orr < R) out[(size_t)oc * R + orr] = f2bf_u(tile[tx][i]);
  }
}

// ---------------- P4: bias2[do] = 4*sum_dm conv_b[dm]*wd[dm][do] + bd[do] ----------------
__global__ void k_bias2(const float* __restrict__ conv_b, const float* __restrict__ wd,
                        const float* __restrict__ bd, float* __restrict__ bias2) {
  int o = blockIdx.x * 256 + threadIdx.x;
  if (o >= D_DIM) return;
  float acc = 0.f;
  for (int dm = 0; dm < D_DIM; ++dm) acc += conv_b[dm] * wd[(size_t)dm * D_DIM + o];
  bias2[o] = 4.f * acc + bd[o];
}

// ---------------- P2: W2 GEMM ----------------
// C[do][j'] = sum_dm wdT[do][dm] * cwT[j'][dm],  j' = di*3+k
// stored permuted: BmatT[do][k*768+di] (bf16), the B^T operand of the main GEMM.
__global__ __launch_bounds__(256) void k_gemm_w2(
    const unsigned short* __restrict__ wdT, const unsigned short* __restrict__ cwT,
    unsigned short* __restrict__ BmatT) {
  __shared__ unsigned short sA[128 * 32];
  __shared__ unsigned short sB[128 * 32];
  const int bid = blockIdx.x;
  const int bm = bid / 18, bn = bid - bm * 18;
  const int t = threadIdx.x;
  const int lane = t & 63, w = t >> 6;
  const int wr = w >> 1, wc = w & 1;
  const int lr = lane & 15, lg = lane >> 4;

  const int c0 = t, c1 = t + 256;
  const unsigned short* aB0 = wdT + (size_t)(bm * 128 + (c0 >> 2)) * 768 + (c0 & 3) * 8;
  const unsigned short* aB1 = wdT + (size_t)(bm * 128 + (c1 >> 2)) * 768 + (c1 & 3) * 8;
  const unsigned short* bB0 = cwT + (size_t)(bn * 128 + (c0 >> 2)) * 768 + (c0 & 3) * 8;
  const unsigned short* bB1 = cwT + (size_t)(bn * 128 + (c1 >> 2)) * 768 + (c1 & 3) * 8;

  f32x4 acc[4][4] = {};
  int aOff[4], bOff[4];
#pragma unroll
  for (int i = 0; i < 4; ++i) {
    aOff[i] = (wr * 64 + i * 16 + lr) * 4 + lg;
    bOff[i] = (wc * 64 + i * 16 + lr) * 4 + lg;
  }
  const bf16x8* At = (const bf16x8*)sA;
  const bf16x8* Bt = (const bf16x8*)sB;

  for (int kt = 0; kt < 24; ++kt) {
    const int ko = kt * 32;
    __syncthreads();
    async16(aB0 + ko, &sA[c0 * 8]);
    async16(aB1 + ko, &sA[c1 * 8]);
    async16(bB0 + ko, &sB[c0 * 8]);
    async16(bB1 + ko, &sB[c1 * 8]);
    __syncthreads();
    bf16x8 av[4], bv[4];
#pragma unroll
    for (int i = 0; i < 4; ++i) { av[i] = At[aOff[i]]; bv[i] = Bt[bOff[i]]; }
#pragma unroll
    for (int mi = 0; mi < 4; ++mi)
#pragma unroll
      for (int ni = 0; ni < 4; ++ni)
        acc[mi][ni] = __builtin_amdgcn_mfma_f32_16x16x32_bf16(av[mi], bv[ni], acc[mi][ni], 0, 0, 0);
  }

#pragma unroll
  for (int mi = 0; mi < 4; ++mi) {
    const int row0 = bm * 128 + wr * 64 + mi * 16 + lg * 4;  // do
#pragma unroll
    for (int ni = 0; ni < 4; ++ni) {
      const int jp = bn * 128 + wc * 64 + ni * 16 + lr;      // j' = di*3+k
      const int di = jp / 3;
      const int kk = jp - di * 3;
      const int j = kk * 768 + di;
      f32x4 v = acc[mi][ni];
#pragma unroll
      for (int i = 0; i < 4; ++i)
        BmatT[(size_t)(row0 + i) * KDIM + j] = f2bf_u(v[i]);
    }
  }
}

// ---------------- P3: main conv-as-GEMM ----------------
// Y[m=(n,l)][do] = sum_{j=k*768+di} Xpad[n][l+k][di] * BmatT[do][j],  fp32 out into d_out
__global__ __launch_bounds__(256) void k_gemm_conv(
    const unsigned short* __restrict__ Xpad, const unsigned short* __restrict__ BmatT,
    float* __restrict__ Y) {
  __shared__ unsigned short sA[128 * 32];
  __shared__ unsigned short sB[128 * 32];
  const int bid = blockIdx.x;
  const int bm = bid / 6, bn = bid - bm * 6;
  const int t = threadIdx.x;
  const int lane = t & 63, w = t >> 6;
  const int wr = w >> 1, wc = w & 1;
  const int lr = lane & 15, lg = lane >> 4;

  const int c0 = t, c1 = t + 256;
  int r0 = bm * 128 + (c0 >> 2); if (r0 >= M_ROWS) r0 = M_ROWS - 1;
  int r1 = bm * 128 + (c1 >> 2); if (r1 >= M_ROWS) r1 = M_ROWS - 1;
  const int n0 = r0 / L_SEQ, ll0 = r0 - n0 * L_SEQ;
  const int n1 = r1 / L_SEQ, ll1 = r1 - n1 * L_SEQ;
  // A row (n,l) starts at Xpad[n][l][0] and spans 2304 contiguous elements (rows l..l+2)
  const unsigned short* aB0 = Xpad + ((size_t)n0 * LPAD + ll0) * D_DIM + (c0 & 3) * 8;
  const unsigned short* aB1 = Xpad + ((size_t)n1 * LPAD + ll1) * D_DIM + (c1 & 3) * 8;
  const unsigned short* bB0 = BmatT + (size_t)(bn * 128 + (c0 >> 2)) * KDIM + (c0 & 3) * 8;
  const unsigned short* bB1 = BmatT + (size_t)(bn * 128 + (c1 >> 2)) * KDIM + (c1 & 3) * 8;

  f32x4 acc[4][4] = {};
  int aOff[4], bOff[4];
#pragma unroll
  for (int i = 0; i < 4; ++i) {
    aOff[i] = (wr * 64 + i * 16 + lr) * 4 + lg;
    bOff[i] = (wc * 64 + i * 16 + lr) * 4 + lg;
  }
  const bf16x8* At = (const bf16x8*)sA;
  const bf16x8* Bt = (const bf16x8*)sB;

  for (int kt = 0; kt < 72; ++kt) {
    const int ko = kt * 32;
    __syncthreads();
    async16(aB0 + ko, &sA[c0 * 8]);
    async16(aB1 + ko, &sA[c1 * 8]);
    async16(bB0 + ko, &sB[c0 * 8]);
    async16(bB1 + ko, &sB[c1 * 8]);
    __syncthreads();
    bf16x8 av[4], bv[4];
#pragma unroll
    for (int i = 0; i < 4; ++i) { av[i] = At[aOff[i]]; bv[i] = Bt[bOff[i]]; }
#pragma unroll
    for (int mi = 0; mi < 4; ++mi)
#pragma unroll
      for (int ni = 0; ni < 4; ++ni)
        acc[mi][ni] = __builtin_amdgcn_mfma_f32_16x16x32_bf16(av[mi], bv[ni], acc[mi][ni], 0, 0, 0);
  }

#pragma unroll
  for (int mi = 0; mi < 4; ++mi) {
    const int row0 = bm * 128 + wr * 64 + mi * 16 + lg * 4;
#pragma unroll
    for (int ni = 0; ni < 4; ++ni) {
      const int col = bn * 128 + wc * 64 + ni * 16 + lr;
      f32x4 v = acc[mi][ni];
#pragma unroll
      for (int i = 0; i < 4; ++i) {
        const int gm = row0 + i;
        if (gm < M_ROWS) Y[(size_t)gm * D_DIM + col] = v[i];
      }
    }
  }
}

// ---------------- P6: in-place pooling + bias on d_out ----------------
// out[l] = y[l] + mean2 + mean3 + mean4 + bias2 over aligned groups of 12 l's
__global__ __launch_bounds__(192) void k_pool(float* __restrict__ Y,
                                              const float* __restrict__ bias2) {
  const int b = blockIdx.x;
  const int n = b / 170, g = b - n * 170;
  const int t = threadIdx.x;  // do4 chunk 0..191
  const size_t base = ((size_t)n * L_SEQ + (size_t)g * 12) * D_DIM + (size_t)t * 4;

  f32x4 y[12];
#pragma unroll
  for (int i = 0; i < 12; ++i) y[i] = *(const f32x4*)&Y[base + (size_t)i * D_DIM];
  const f32x4 bias = *(const f32x4*)&bias2[t * 4];

  f32x4 m2[6], m3[4], m4[3];
#pragma unroll
  for (int j = 0; j < 6; ++j) m2[j] = (y[2 * j] + y[2 * j + 1]) * 0.5f;
#pragma unroll
  for (int j = 0; j < 4; ++j) m3[j] = (y[3 * j] + y[3 * j + 1] + y[3 * j + 2]) * (1.f / 3.f);
#pragma unroll
  for (int j = 0; j < 3; ++j) m4[j] = (y[4 * j] + y[4 * j + 1] + y[4 * j + 2] + y[4 * j + 3]) * 0.25f;

#pragma unroll
  for (int i = 0; i < 12; ++i) {
    f32x4 o = y[i] + m2[i >> 1] + m3[i / 3] + m4[i >> 2] + bias;
    *(f32x4*)&Y[base + (size_t)i * D_DIM] = o;
  }
}

// ---------------- launch ----------------
extern "C" void kernel_launch(void* const* d_in, const int* in_sizes, int n_in,
                              void* d_out, int out_size, void* d_ws, size_t ws_size,
                              hipStream_t stream) {
  const float* X      = (const float*)d_in[0];
  const float* conv_w = (const float*)d_in[1];
  const float* conv_b = (const float*)d_in[2];
  // d_in[3] = wr, d_in[4] = br: analytically dead (softmax over size-1 axis == 1)
  const float* wd     = (const float*)d_in[5];
  const float* bd     = (const float*)d_in[6];
  float* out = (float*)d_out;

  // workspace carve (all offsets 256B-aligned)
  const size_t off_Xpad  = 0;                        // 8*2042*768 bf16 = 25,092,096 B
  const size_t off_wdT   = 25092096;                 // 768*768 bf16    =  1,179,648 B
  const size_t off_cwT   = 26271744;                 // 2304*768 bf16   =  3,538,944 B
  const size_t off_BmatT = 29810688;                 // 768*2304 bf16   =  3,538,944 B
  const size_t off_bias2 = 33349632;                 // 768 f32         =      3,072 B
  const size_t NEED      = 33352704;
  if (ws_size < NEED) return;  // leaves d_out poisoned -> loud failure instead of OOB writes

  char* ws = (char*)d_ws;
  unsigned short* Xpad  = (unsigned short*)(ws + off_Xpad);
  unsigned short* wdT   = (unsigned short*)(ws + off_wdT);
  unsigned short* cwT   = (unsigned short*)(ws + off_cwT);
  unsigned short* BmatT = (unsigned short*)(ws + off_BmatT);
  float*          bias2 = (float*)(ws + off_bias2);

  k_pad<<<12252, 256, 0, stream>>>(X, Xpad);
  dim3 tb(32, 8);
  k_transpose<<<dim3(24, 24), tb, 0, stream>>>(wd, wdT, 768, 768);       // wdT[do][dm]
  k_transpose<<<dim3(72, 24), tb, 0, stream>>>(conv_w, cwT, 768, 2304);  // cwT[j'][dm]
  k_bias2<<<3, 256, 0, stream>>>(conv_b, wd, bd, bias2);
  k_gemm_w2<<<6 * 18, 256, 0, stream>>>(wdT, cwT, BmatT);
  k_gemm_conv<<<128 * 6, 256, 0, stream>>>(Xpad, BmatT, out);
  k_pool<<<8 * 170, 192, 0, stream>>>(out, bias2);
}

// Round 2
// 180.203 us; speedup vs baseline: 1.2024x; 1.2024x over previous
//
#include <hip/hip_runtime.h>

#define N_B    8
#define L_SEQ  2040
#define D_DIM  768
#define KDIM   2304      // 3*768
#define M_ROWS 16320     // N_B*L_SEQ
#define LPAD   2042      // L_SEQ + 2 zero guard rows

typedef __bf16 bf16x8 __attribute__((ext_vector_type(8)));
typedef float  f32x4  __attribute__((ext_vector_type(4)));

__device__ __forceinline__ unsigned short f2bf_u(float f) {
  union { float f; unsigned u; } v; v.f = f;
  unsigned u = v.u;
  return (unsigned short)((u + 0x7FFFu + ((u >> 16) & 1u)) >> 16);
}

__device__ __forceinline__ void async16(const unsigned short* g, unsigned short* l) {
  __builtin_amdgcn_global_load_lds(
      (const __attribute__((address_space(1))) void*)g,
      (__attribute__((address_space(3))) void*)l, 16, 0, 0);
}

// ---------------- P0: pad + fp32->bf16 convert X ----------------
__global__ void k_pad(const float* __restrict__ X, unsigned short* __restrict__ Xpad) {
  size_t idx = ((size_t)blockIdx.x * 256 + threadIdx.x) * 4;
  const size_t per_n = (size_t)LPAD * D_DIM;
  if (idx >= (size_t)N_B * per_n) return;
  int n = (int)(idx / per_n);
  size_t rem = idx - (size_t)n * per_n;
  int lp = (int)(rem / D_DIM);
  int d  = (int)(rem - (size_t)lp * D_DIM);
  ushort4 o;
  if (lp == 0 || lp == LPAD - 1) {
    o.x = 0; o.y = 0; o.z = 0; o.w = 0;
  } else {
    const float4 f = *(const float4*)&X[((size_t)n * L_SEQ + (lp - 1)) * D_DIM + d];
    o.x = f2bf_u(f.x); o.y = f2bf_u(f.y); o.z = f2bf_u(f.z); o.w = f2bf_u(f.w);
  }
  *(ushort4*)&Xpad[idx] = o;
}

// ---------------- P1: fp32 [R][C] -> bf16 transposed [C][R] ----------------
__global__ void k_transpose(const float* __restrict__ in, unsigned short* __restrict__ out,
                            int R, int C) {
  __shared__ float tile[32][33];
  int tx = threadIdx.x, ty = threadIdx.y;
  int c0 = blockIdx.x * 32;
  int r0 = blockIdx.y * 32;
  for (int i = ty; i < 32; i += 8) {
    int r = r0 + i, c = c0 + tx;
    tile[i][tx] = (r < R && c < C) ? in[(size_t)r * C + c] : 0.f;
  }
  __syncthreads();
  for (int i = ty; i < 32; i += 8) {
    int oc = c0 + i;
    int orr = r0 + tx;
    if (oc < C && orr < R) out[(size_t)oc * R + orr] = f2bf_u(tile[tx][i]);
  }
}

// ---------------- P4: bias2[do] = 4*sum_dm conv_b[dm]*wd[dm][do] + bd[do] ----------------
__global__ void k_bias2(const float* __restrict__ conv_b, const float* __restrict__ wd,
                        const float* __restrict__ bd, float* __restrict__ bias2) {
  int o = blockIdx.x * 256 + threadIdx.x;
  if (o >= D_DIM) return;
  float acc = 0.f;
  for (int dm = 0; dm < D_DIM; ++dm) acc += conv_b[dm] * wd[(size_t)dm * D_DIM + o];
  bias2[o] = 4.f * acc + bd[o];
}

// ---------------- P2: W2 GEMM (m97-style 128^2) ----------------
__global__ __launch_bounds__(256) void k_gemm_w2(
    const unsigned short* __restrict__ wdT, const unsigned short* __restrict__ cwT,
    unsigned short* __restrict__ BmatT) {
  __shared__ unsigned short sA[128 * 32];
  __shared__ unsigned short sB[128 * 32];
  const int bid = blockIdx.x;
  const int bm = bid / 18, bn = bid - bm * 18;
  const int t = threadIdx.x;
  const int lane = t & 63, w = t >> 6;
  const int wr = w >> 1, wc = w & 1;
  const int lr = lane & 15, lg = lane >> 4;

  const int c0 = t, c1 = t + 256;
  const unsigned short* aB0 = wdT + (size_t)(bm * 128 + (c0 >> 2)) * 768 + (c0 & 3) * 8;
  const unsigned short* aB1 = wdT + (size_t)(bm * 128 + (c1 >> 2)) * 768 + (c1 & 3) * 8;
  const unsigned short* bB0 = cwT + (size_t)(bn * 128 + (c0 >> 2)) * 768 + (c0 & 3) * 8;
  const unsigned short* bB1 = cwT + (size_t)(bn * 128 + (c1 >> 2)) * 768 + (c1 & 3) * 8;

  f32x4 acc[4][4] = {};
  int aOff[4], bOff[4];
#pragma unroll
  for (int i = 0; i < 4; ++i) {
    aOff[i] = (wr * 64 + i * 16 + lr) * 4 + lg;
    bOff[i] = (wc * 64 + i * 16 + lr) * 4 + lg;
  }
  const bf16x8* At = (const bf16x8*)sA;
  const bf16x8* Bt = (const bf16x8*)sB;

  for (int kt = 0; kt < 24; ++kt) {
    const int ko = kt * 32;
    __syncthreads();
    async16(aB0 + ko, &sA[c0 * 8]);
    async16(aB1 + ko, &sA[c1 * 8]);
    async16(bB0 + ko, &sB[c0 * 8]);
    async16(bB1 + ko, &sB[c1 * 8]);
    __syncthreads();
    bf16x8 av[4], bv[4];
#pragma unroll
    for (int i = 0; i < 4; ++i) { av[i] = At[aOff[i]]; bv[i] = Bt[bOff[i]]; }
#pragma unroll
    for (int mi = 0; mi < 4; ++mi)
#pragma unroll
      for (int ni = 0; ni < 4; ++ni)
        acc[mi][ni] = __builtin_amdgcn_mfma_f32_16x16x32_bf16(av[mi], bv[ni], acc[mi][ni], 0, 0, 0);
  }

#pragma unroll
  for (int mi = 0; mi < 4; ++mi) {
    const int row0 = bm * 128 + wr * 64 + mi * 16 + lg * 4;
#pragma unroll
    for (int ni = 0; ni < 4; ++ni) {
      const int jp = bn * 128 + wc * 64 + ni * 16 + lr;
      const int di = jp / 3;
      const int kk = jp - di * 3;
      const int j = kk * 768 + di;
      f32x4 v = acc[mi][ni];
#pragma unroll
      for (int i = 0; i < 4; ++i)
        BmatT[(size_t)(row0 + i) * KDIM + j] = f2bf_u(v[i]);
    }
  }
}

// ---------------- P3: main conv-as-GEMM, 256x256 tile, 8-wave, 4-phase/K-tile ----------------
// LDS frag-block layout per (buf, op, khalf): 16 blocks of 1024B; block b holds rows
// b*16..b*16+15; lane l of a block = row (l&15), k-octet (l>>4). ds_read = base + l*16
// (conflict-free). global_load_lds fills it linearly; source addr per chunk derived below.
__global__ __launch_bounds__(512, 2) void k_gemm_conv8(
    const unsigned short* __restrict__ Xpad, const unsigned short* __restrict__ BmatT,
    float* __restrict__ Y) {
  __shared__ unsigned short lds[65536];  // 128 KiB: [2 buf][2 op][2 kh][16 KiB]
  char* ldsc = (char*)lds;

  const int tid = threadIdx.x;
  const int lane = tid & 63;
  const int wid = tid >> 6;
  const int wr = wid >> 2, wc = wid & 3;

  // bijective XCD swizzle (192 % 8 == 0): chunk of 24 logical ids per XCD shares all 3 B panels
  const int bid = blockIdx.x;
  const int swz = (bid & 7) * 24 + (bid >> 3);
  const int bm = swz / 3, bn = swz - bm * 3;

  // ---- staging source precompute ----
  // chunk c = r*512 + tid (r=0,1): frag-block = c>>6, row_local = (c>>6)*16 + (c&15),
  // k-octet = (c>>4)&3. For r0: block = wid, for r1: block = wid + 8.
  const int koct = lane >> 4;
  const int rl0 = wid * 16 + (lane & 15);
  const int rl1 = rl0 + 128;
  int m0 = bm * 256 + rl0; if (m0 > M_ROWS - 1) m0 = M_ROWS - 1;
  int m1 = bm * 256 + rl1; if (m1 > M_ROWS - 1) m1 = M_ROWS - 1;
  const int n0 = m0 / L_SEQ, l0 = m0 - n0 * L_SEQ;
  const int n1 = m1 / L_SEQ, l1 = m1 - n1 * L_SEQ;
  const unsigned short* aS0 = Xpad + (size_t)(n0 * LPAD + l0) * D_DIM + koct * 8;
  const unsigned short* aS1 = Xpad + (size_t)(n1 * LPAD + l1) * D_DIM + koct * 8;
  const unsigned short* bS0 = BmatT + (size_t)(bn * 256 + rl0) * KDIM + koct * 8;
  const unsigned short* bS1 = BmatT + (size_t)(bn * 256 + rl1) * KDIM + koct * 8;
  const int dst0 = tid * 16;          // byte offset of chunk r0 within a 16 KiB region
  const int dst1 = dst0 + 8192;       // chunk r1

  // ds_read bases (bytes within buf): A at +0, B at +32768; + kh*16384 + block*1024 + lane*16
  const int aRd = wr * 8192 + lane * 16;           // wr*8 blocks
  const int bRd = wc * 4096 + lane * 16;           // wc*4 blocks

  f32x4 acc[8][4] = {};
  bf16x8 av[8], bv[2];

#define STG_A(nb, kh, koff) do { \
    async16(aS0 + (koff), (unsigned short*)(ldsc + (nb) * 65536 + (kh) * 16384 + dst0)); \
    async16(aS1 + (koff), (unsigned short*)(ldsc + (nb) * 65536 + (kh) * 16384 + dst1)); } while (0)
#define STG_B(nb, kh, koff) do { \
    async16(bS0 + (koff), (unsigned short*)(ldsc + (nb) * 65536 + 32768 + (kh) * 16384 + dst0)); \
    async16(bS1 + (koff), (unsigned short*)(ldsc + (nb) * 65536 + 32768 + (kh) * 16384 + dst1)); } while (0)
#define LD_AV(kh) \
    _Pragma("unroll") \
    for (int mi = 0; mi < 8; ++mi) \
      av[mi] = *(const bf16x8*)(ldsc + cbyt + (kh) * 16384 + aRd + mi * 1024);
#define LD_BV(kh, nh) \
    bv[0] = *(const bf16x8*)(ldsc + cbyt + 32768 + (kh) * 16384 + bRd + (2 * (nh)) * 1024); \
    bv[1] = *(const bf16x8*)(ldsc + cbyt + 32768 + (kh) * 16384 + bRd + (2 * (nh) + 1) * 1024);
#define MF16(nh) \
    __builtin_amdgcn_s_setprio(1); \
    _Pragma("unroll") \
    for (int mi = 0; mi < 8; ++mi) { \
      acc[mi][2 * (nh)]     = __builtin_amdgcn_mfma_f32_16x16x32_bf16(av[mi], bv[0], acc[mi][2 * (nh)], 0, 0, 0); \
      acc[mi][2 * (nh) + 1] = __builtin_amdgcn_mfma_f32_16x16x32_bf16(av[mi], bv[1], acc[mi][2 * (nh) + 1], 0, 0, 0); \
    } \
    __builtin_amdgcn_s_setprio(0);
#define BARR asm volatile("s_barrier" ::: "memory")
#define VM4  asm volatile("s_waitcnt vmcnt(4)" ::: "memory")
#define VM0  asm volatile("s_waitcnt vmcnt(0)" ::: "memory")

  // prologue: stage all 4 halves of tile 0 into buf 0; vmcnt(4) covers A-k0,B-k0
  STG_A(0, 0, 0); STG_B(0, 0, 0); STG_A(0, 1, 32); STG_B(0, 1, 32);
  VM4;
  BARR;

  for (int t = 0; t < 36; ++t) {
    const int cur = t & 1;
    const int nb = cur ^ 1;
    const int cbyt = cur * 65536;
    const int ko = (t + 1) * 64;
    const bool st = (t < 35);
    // ---- q0: kh0, n-half 0 ----
    LD_AV(0); LD_BV(0, 0);
    if (st) STG_A(nb, 0, ko);
    BARR;
    MF16(0);
    BARR;
    // ---- q1: kh0, n-half 1 ----
    LD_BV(0, 1);
    if (st) STG_B(nb, 0, ko);
    BARR;
    MF16(1);
    if (st) { VM4; } else { VM0; }   // guarantees kh1 halves of tile t
    BARR;
    // ---- q2: kh1, n-half 0 ----
    LD_AV(1); LD_BV(1, 0);
    if (st) STG_A(nb, 1, ko + 32);
    BARR;
    MF16(0);
    BARR;
    // ---- q3: kh1, n-half 1 ----
    LD_BV(1, 1);
    if (st) STG_B(nb, 1, ko + 32);
    BARR;
    MF16(1);
    VM4;                              // guarantees A-k0,B-k0 of tile t+1 (no-op at t=35)
    BARR;
  }

  // epilogue: C[row][col], row = rb + mi*16 + i, col = colb + ni*16
  const int lr = lane & 15, lg = lane >> 4;
  const int rb = bm * 256 + wr * 128 + lg * 4;
  const int colb = bn * 256 + wc * 64 + lr;
#pragma unroll
  for (int mi = 0; mi < 8; ++mi) {
#pragma unroll
    for (int i = 0; i < 4; ++i) {
      const int gm = rb + mi * 16 + i;
      if (gm < M_ROWS) {
        float* yp = Y + (size_t)gm * D_DIM + colb;
        yp[0]  = acc[mi][0][i];
        yp[16] = acc[mi][1][i];
        yp[32] = acc[mi][2][i];
        yp[48] = acc[mi][3][i];
      }
    }
  }
#undef STG_A
#undef STG_B
#undef LD_AV
#undef LD_BV
#undef MF16
#undef BARR
#undef VM4
#undef VM0
}

// ---------------- P6: in-place pooling + bias on d_out ----------------
__global__ __launch_bounds__(192) void k_pool(float* __restrict__ Y,
                                              const float* __restrict__ bias2) {
  const int b = blockIdx.x;
  const int n = b / 170, g = b - n * 170;
  const int t = threadIdx.x;
  const size_t base = ((size_t)n * L_SEQ + (size_t)g * 12) * D_DIM + (size_t)t * 4;

  f32x4 y[12];
#pragma unroll
  for (int i = 0; i < 12; ++i) y[i] = *(const f32x4*)&Y[base + (size_t)i * D_DIM];
  const f32x4 bias = *(const f32x4*)&bias2[t * 4];

  f32x4 m2[6], m3[4], m4[3];
#pragma unroll
  for (int j = 0; j < 6; ++j) m2[j] = (y[2 * j] + y[2 * j + 1]) * 0.5f;
#pragma unroll
  for (int j = 0; j < 4; ++j) m3[j] = (y[3 * j] + y[3 * j + 1] + y[3 * j + 2]) * (1.f / 3.f);
#pragma unroll
  for (int j = 0; j < 3; ++j) m4[j] = (y[4 * j] + y[4 * j + 1] + y[4 * j + 2] + y[4 * j + 3]) * 0.25f;

#pragma unroll
  for (int i = 0; i < 12; ++i) {
    f32x4 o = y[i] + m2[i >> 1] + m3[i / 3] + m4[i >> 2] + bias;
    *(f32x4*)&Y[base + (size_t)i * D_DIM] = o;
  }
}

// ---------------- launch ----------------
extern "C" void kernel_launch(void* const* d_in, const int* in_sizes, int n_in,
                              void* d_out, int out_size, void* d_ws, size_t ws_size,
                              hipStream_t stream) {
  const float* X      = (const float*)d_in[0];
  const float* conv_w = (const float*)d_in[1];
  const float* conv_b = (const float*)d_in[2];
  // d_in[3] = wr, d_in[4] = br: analytically dead (softmax over size-1 axis == 1)
  const float* wd     = (const float*)d_in[5];
  const float* bd     = (const float*)d_in[6];
  float* out = (float*)d_out;

  const size_t off_Xpad  = 0;
  const size_t off_wdT   = 25092096;
  const size_t off_cwT   = 26271744;
  const size_t off_BmatT = 29810688;
  const size_t off_bias2 = 33349632;
  const size_t NEED      = 33352704;
  if (ws_size < NEED) return;

  char* ws = (char*)d_ws;
  unsigned short* Xpad  = (unsigned short*)(ws + off_Xpad);
  unsigned short* wdT   = (unsigned short*)(ws + off_wdT);
  unsigned short* cwT   = (unsigned short*)(ws + off_cwT);
  unsigned short* BmatT = (unsigned short*)(ws + off_BmatT);
  float*          bias2 = (float*)(ws + off_bias2);

  k_pad<<<12252, 256, 0, stream>>>(X, Xpad);
  dim3 tb(32, 8);
  k_transpose<<<dim3(24, 24), tb, 0, stream>>>(wd, wdT, 768, 768);
  k_transpose<<<dim3(72, 24), tb, 0, stream>>>(conv_w, cwT, 768, 2304);
  k_bias2<<<3, 256, 0, stream>>>(conv_b, wd, bd, bias2);
  k_gemm_w2<<<6 * 18, 256, 0, stream>>>(wdT, cwT, BmatT);
  k_gemm_conv8<<<192, 512, 0, stream>>>(Xpad, BmatT, out);
  k_pool<<<8 * 170, 192, 0, stream>>>(out, bias2);
}

// Round 4
// 98.477 us; speedup vs baseline: 2.2002x; 1.8299x over previous
//
#include <hip/hip_runtime.h>

#define N_B    8
#define L_SEQ  2040
#define D_DIM  768
#define KDIM   2304      // 3*768
#define M_ROWS 16320     // N_B*L_SEQ
#define LPAD   2042      // L_SEQ + 2 zero guard rows

typedef __bf16 bf16x8 __attribute__((ext_vector_type(8)));
typedef float  f32x4  __attribute__((ext_vector_type(4)));

__device__ __forceinline__ unsigned short f2bf_u(float f) {
  union { float f; unsigned u; } v; v.f = f;
  unsigned u = v.u;
  return (unsigned short)((u + 0x7FFFu + ((u >> 16) & 1u)) >> 16);
}

__device__ __forceinline__ void async16(const unsigned short* g, const unsigned char* l) {
  __builtin_amdgcn_global_load_lds(
      (const __attribute__((address_space(1))) void*)g,
      (__attribute__((address_space(3))) void*)l, 16, 0, 0);
}

// ---------------- P0: pad + fp32->bf16 convert X ----------------
__global__ void k_pad(const float* __restrict__ X, unsigned short* __restrict__ Xpad) {
  size_t idx = ((size_t)blockIdx.x * 256 + threadIdx.x) * 4;
  const size_t per_n = (size_t)LPAD * D_DIM;
  int n = (int)(idx / per_n);
  size_t rem = idx - (size_t)n * per_n;
  int lp = (int)(rem / D_DIM);
  int d  = (int)(rem - (size_t)lp * D_DIM);
  ushort4 o;
  if (lp == 0 || lp == LPAD - 1) {
    o.x = 0; o.y = 0; o.z = 0; o.w = 0;
  } else {
    const float4 f = *(const float4*)&X[((size_t)n * L_SEQ + (lp - 1)) * D_DIM + d];
    o.x = f2bf_u(f.x); o.y = f2bf_u(f.y); o.z = f2bf_u(f.z); o.w = f2bf_u(f.w);
  }
  *(ushort4*)&Xpad[idx] = o;
}

// ---------------- P1: both weight transposes in one launch (z selects) ----------------
__global__ void k_tr2(const float* __restrict__ wd, unsigned short* __restrict__ wdT,
                      const float* __restrict__ cw, unsigned short* __restrict__ cwT) {
  __shared__ float tile[32][33];
  const int z = blockIdx.z;
  const float* in = z ? cw : wd;
  unsigned short* out = z ? cwT : wdT;
  const int R = 768, C = z ? 2304 : 768;
  if (!z && blockIdx.x >= 24) return;
  int tx = threadIdx.x, ty = threadIdx.y;
  int c0 = blockIdx.x * 32;
  int r0 = blockIdx.y * 32;
  for (int i = ty; i < 32; i += 8) {
    int r = r0 + i, c = c0 + tx;
    tile[i][tx] = (r < R && c < C) ? in[(size_t)r * C + c] : 0.f;
  }
  __syncthreads();
  for (int i = ty; i < 32; i += 8) {
    int oc = c0 + i;
    int orr = r0 + tx;
    if (oc < C && orr < R) out[(size_t)oc * R + orr] = f2bf_u(tile[tx][i]);
  }
}

// ---------------- P2: W2 GEMM -> pre-blocked Bblk (blocks 0..107) + bias2 (108..119) ----
// Bblk element (p,kt,kh,blk,lane=o*16+r,e) = W2[do = p*256+blk*16+r][j = kt*64+kh*32+o*8+e]
// where W2[do][j], j = kk*768+di, is the fused conv*wd weight. This is the exact LDS image
// the main GEMM stages, so B staging becomes fully-contiguous 1KB per wave-instr.
__global__ __launch_bounds__(256) void k_w2b(
    const unsigned short* __restrict__ wdT, const unsigned short* __restrict__ cwT,
    unsigned short* __restrict__ Bblk,
    const float* __restrict__ conv_b, const float* __restrict__ wd,
    const float* __restrict__ bd, float* __restrict__ bias2) {
  __shared__ unsigned short sA[128 * 32];
  __shared__ unsigned short sB[128 * 32];
  __shared__ float red[256];
  const int bid = blockIdx.x;
  const int t = threadIdx.x;

  if (bid >= 108) {   // ---- bias2: 12 blocks, 4 dm-slices per output col ----
    const int b2 = bid - 108;
    const int o = b2 * 64 + (t & 63);
    const int sl = t >> 6;
    float acc = 0.f;
    for (int dm = sl * 192; dm < sl * 192 + 192; ++dm)
      acc += conv_b[dm] * wd[(size_t)dm * D_DIM + o];
    red[t] = acc;
    __syncthreads();
    if (t < 64)
      bias2[o] = 4.f * (red[t] + red[t + 64] + red[t + 128] + red[t + 192]) + bd[o];
    return;
  }

  const int bm = bid / 18, bn = bid - bm * 18;
  const int lane = t & 63, w = t >> 6;
  const int wr = w >> 1, wc = w & 1;
  const int lr = lane & 15, lg = lane >> 4;

  const int c0 = t, c1 = t + 256;
  const unsigned short* aB0 = wdT + (size_t)(bm * 128 + (c0 >> 2)) * 768 + (c0 & 3) * 8;
  const unsigned short* aB1 = wdT + (size_t)(bm * 128 + (c1 >> 2)) * 768 + (c1 & 3) * 8;
  const unsigned short* bB0 = cwT + (size_t)(bn * 128 + (c0 >> 2)) * 768 + (c0 & 3) * 8;
  const unsigned short* bB1 = cwT + (size_t)(bn * 128 + (c1 >> 2)) * 768 + (c1 & 3) * 8;

  f32x4 acc[4][4] = {};
  int aOff[4], bOff[4];
#pragma unroll
  for (int i = 0; i < 4; ++i) {
    aOff[i] = (wr * 64 + i * 16 + lr) * 4 + lg;
    bOff[i] = (wc * 64 + i * 16 + lr) * 4 + lg;
  }
  const bf16x8* At = (const bf16x8*)sA;
  const bf16x8* Bt = (const bf16x8*)sB;

  for (int kt = 0; kt < 24; ++kt) {
    const int ko = kt * 32;
    __syncthreads();
    async16(aB0 + ko, (const unsigned char*)&sA[c0 * 8]);
    async16(aB1 + ko, (const unsigned char*)&sA[c1 * 8]);
    async16(bB0 + ko, (const unsigned char*)&sB[c0 * 8]);
    async16(bB1 + ko, (const unsigned char*)&sB[c1 * 8]);
    __syncthreads();
    bf16x8 av[4], bv[4];
#pragma unroll
    for (int i = 0; i < 4; ++i) { av[i] = At[aOff[i]]; bv[i] = Bt[bOff[i]]; }
#pragma unroll
    for (int mi = 0; mi < 4; ++mi)
#pragma unroll
      for (int ni = 0; ni < 4; ++ni)
        acc[mi][ni] = __builtin_amdgcn_mfma_f32_16x16x32_bf16(av[mi], bv[ni], acc[mi][ni], 0, 0, 0);
  }

#pragma unroll
  for (int ni = 0; ni < 4; ++ni) {
    const int jp = bn * 128 + wc * 64 + ni * 16 + lr;   // j' = di*3+kk
    const int di = jp / 3;
    const int kk = jp - di * 3;
    const int j = kk * 768 + di;                         // GEMM k index
    const int kt2 = j >> 6, rem = j & 63;
    const int kh = rem >> 5, o = (rem >> 3) & 3, e = rem & 7;
    const size_t jbase = (size_t)kt2 * 16384 + kh * 8192 + o * 128 + e;  // + blk*512 + r*8
#pragma unroll
    for (int mi = 0; mi < 4; ++mi) {
      const int row0 = bm * 128 + wr * 64 + mi * 16 + lg * 4;            // do
      f32x4 v = acc[mi][ni];
#pragma unroll
      for (int i = 0; i < 4; ++i) {
        const int dd = row0 + i;
        const int p = dd >> 8, cl = dd & 255, blk = cl >> 4, r = cl & 15;
        Bblk[(size_t)p * 589824 + jbase + blk * 512 + r * 8] = f2bf_u(v[i]);
      }
    }
  }
}

// ---------------- P3: conv-GEMM 192x256 tile + fused pooling epilogue ----------------
// LDS per buf (56KB): A at +0: [2 kh][12 blk][1024B]; B at +24576: [2 kh][16 blk][1024B].
// Block = 64 lanes x 16B; lane l -> row/col (l&15), k-octet (l>>4). All ds_reads are
// base + l*16 (linear, conflict-free); global_load_lds fills linearly (dst = tid*16).
__global__ __launch_bounds__(512, 2) void k_conv192(
    const unsigned short* __restrict__ Xpad, const unsigned short* __restrict__ Bblk,
    const float* __restrict__ bias2, float* __restrict__ Y) {
  __shared__ unsigned char lds[114688];

  const int tid = threadIdx.x;
  const int lane = tid & 63;
  const int wid = tid >> 6;
  const int wr = wid >> 2, wc = wid & 3;

  // bijective XCD swizzle for 255 blocks (q=31, r=7)
  const int bid = blockIdx.x;
  const int xcd = bid & 7, idx = bid >> 3;
  const int swz = (xcd < 7 ? xcd * 32 : 224 + (xcd - 7) * 31) + idx;
  const int bm = swz / 3, bn = swz - bm * 3;

  // ---- A staging sources: chunk c = rr*512+tid; kh = c/768, q = c%768,
  //      blk = q>>6, lane_in_blk = q&63 -> row = blk*16+(l&15), oct = l>>4 ----
  const unsigned short *aS0, *aS1, *aS2;
  {
#define ACHUNK(rr, dst) { \
    int c = tid + (rr) * 512; \
    int kh = c / 768, q = c - kh * 768; \
    int li = q & 63; \
    int rl = (q >> 6) * 16 + (li & 15); \
    int m = bm * 192 + rl; \
    int n = m / L_SEQ, l = m - n * L_SEQ; \
    dst = Xpad + (size_t)(n * LPAD + l) * D_DIM + kh * 32 + (li >> 4) * 8; }
    ACHUNK(0, aS0) ACHUNK(1, aS1) ACHUNK(2, aS2)
#undef ACHUNK
  }
  // ---- B staging: pre-blocked, purely linear: 32KB per (panel, kt) ----
  const unsigned short* bS = Bblk + (size_t)bn * 589824 + tid * 8;
  const int dA0 = tid * 16, dA1 = dA0 + 8192, dA2 = dA0 + 16384;
  const int dB0 = 24576 + tid * 16, dB1 = dB0 + 8192, dB2 = dB0 + 16384, dB3 = dB0 + 24576;

  // ---- ds_read bases ----
  const int aRd0 = wr * 6144 + lane * 16;            // kh0; +12288 for kh1
  const int bRd0 = 24576 + wc * 4096 + lane * 16;    // kh0; +16384 for kh1

  f32x4 acc[6][4] = {};
  bf16x8 av[6], bv[2];

#define STG(src, koff, dst) async16((src) + (koff), lds + nbb + (dst))
#define LD_AV(kh) \
    _Pragma("unroll") \
    for (int mi = 0; mi < 6; ++mi) \
      av[mi] = *(const bf16x8*)(lds + cb + aRd0 + (kh) * 12288 + mi * 1024);
#define LD_BV(kh, nh) \
    bv[0] = *(const bf16x8*)(lds + cb + bRd0 + (kh) * 16384 + (2 * (nh)) * 1024); \
    bv[1] = *(const bf16x8*)(lds + cb + bRd0 + (kh) * 16384 + (2 * (nh) + 1) * 1024);
#define MF12(nh) \
    __builtin_amdgcn_s_setprio(1); \
    _Pragma("unroll") \
    for (int mi = 0; mi < 6; ++mi) { \
      acc[mi][2 * (nh)]     = __builtin_amdgcn_mfma_f32_16x16x32_bf16(av[mi], bv[0], acc[mi][2 * (nh)], 0, 0, 0); \
      acc[mi][2 * (nh) + 1] = __builtin_amdgcn_mfma_f32_16x16x32_bf16(av[mi], bv[1], acc[mi][2 * (nh) + 1], 0, 0, 0); \
    } \
    __builtin_amdgcn_s_setprio(0);
#define BARR asm volatile("s_barrier" ::: "memory")
#define VM(n) asm volatile("s_waitcnt vmcnt(" #n ")" ::: "memory")
#define LGKM0 asm volatile("s_waitcnt lgkmcnt(0)" ::: "memory")

  // prologue: tile 0 into buf 0, order [A0,A1,B0,B1 | A2,B2,B3]
  {
    const int nbb = 0;
    STG(aS0, 0, dA0); STG(aS1, 0, dA1);
    STG(bS, 0, dB0);  STG(bS, 4096, dB1);
    STG(aS2, 0, dA2);
    STG(bS, 8192, dB2); STG(bS, 12288, dB3);
  }
  VM(3);   // retires A0,A1,B0,B1 -> exactly what q0/q1 read
  BARR;

  for (int t = 0; t < 36; ++t) {
    const int cb = (t & 1) * 57344;
    const int nbb = ((t & 1) ^ 1) * 57344;
    const bool st = (t < 35);
    const int aoff = (t + 1) * 64;          // A: elements along contiguous row-window
    const size_t boff = (size_t)(t + 1) * 16384;  // B: elements per kt image
    // ---- q0: kh0, n-half 0 ----
    LD_AV(0); LD_BV(0, 0);
    if (st) { STG(aS0, aoff, dA0); STG(aS1, aoff, dA1); }
    BARR;
    MF12(0);
    BARR;
    // ---- q1: kh0, n-half 1 ----
    LD_BV(0, 1);
    if (st) { STG(bS, boff, dB0); STG(bS, boff + 4096, dB1); }
    BARR;
    MF12(1);
    if (st) { VM(4); } else { VM(0); }      // retires [A2,B2,B3] of tile t
    BARR;
    // ---- q2: kh1, n-half 0 ----
    LD_AV(1); LD_BV(1, 0);
    if (st) { STG(aS2, aoff, dA2); STG(bS, boff + 8192, dB2); }
    BARR;
    MF12(0);
    BARR;
    // ---- q3: kh1, n-half 1 ----
    LD_BV(1, 1);
    if (st) { STG(bS, boff + 12288, dB3); }
    BARR;
    MF12(1);
    VM(3);                                  // retires [A0,A1,B0,B1] of tile t+1
    BARR;
  }

  // ---- fused pooling epilogue: pass p pools rows [p*96, p*96+96) via LDS [96][256] f32 ----
  const int lr = lane & 15, lg = lane >> 4;
  const f32x4 bias = *(const f32x4*)&bias2[bn * 256 + lane * 4];
#pragma unroll
  for (int p = 0; p < 2; ++p) {
    if (p) { BARR; }  // p=1: pool-reads of p=0 must finish before overwrite
    if (wr == p) {
#pragma unroll
      for (int mi = 0; mi < 6; ++mi)
#pragma unroll
        for (int ni = 0; ni < 4; ++ni)
#pragma unroll
          for (int i = 0; i < 4; ++i)
            *(float*)(lds + ((mi * 16 + lg * 4 + i) * 256 + (wc * 64 + ni * 16 + lr)) * 4) =
                acc[mi][ni][i];
    }
    LGKM0;
    BARR;
    f32x4 y[12];
#pragma unroll
    for (int i = 0; i < 12; ++i)
      y[i] = *(const f32x4*)(lds + ((wid * 12 + i) * 256 + lane * 4) * 4);
    f32x4 m2[6], m3[4], m4[3];
#pragma unroll
    for (int j = 0; j < 6; ++j) m2[j] = (y[2 * j] + y[2 * j + 1]) * 0.5f;
#pragma unroll
    for (int j = 0; j < 4; ++j) m3[j] = (y[3 * j] + y[3 * j + 1] + y[3 * j + 2]) * (1.f / 3.f);
#pragma unroll
    for (int j = 0; j < 3; ++j) m4[j] = (y[4 * j] + y[4 * j + 1] + y[4 * j + 2] + y[4 * j + 3]) * 0.25f;
    const int grow0 = bm * 192 + p * 96 + wid * 12;
#pragma unroll
    for (int i = 0; i < 12; ++i) {
      f32x4 o = y[i] + m2[i >> 1] + m3[i / 3] + m4[i >> 2] + bias;
      *(f32x4*)&Y[(size_t)(grow0 + i) * D_DIM + bn * 256 + lane * 4] = o;
    }
  }
#undef STG
#undef LD_AV
#undef LD_BV
#undef MF12
#undef BARR
#undef VM
#undef LGKM0
}

// ---------------- launch ----------------
extern "C" void kernel_launch(void* const* d_in, const int* in_sizes, int n_in,
                              void* d_out, int out_size, void* d_ws, size_t ws_size,
                              hipStream_t stream) {
  const float* X      = (const float*)d_in[0];
  const float* conv_w = (const float*)d_in[1];
  const float* conv_b = (const float*)d_in[2];
  // d_in[3] = wr, d_in[4] = br: analytically dead (softmax over size-1 axis == 1)
  const float* wd     = (const float*)d_in[5];
  const float* bd     = (const float*)d_in[6];
  float* out = (float*)d_out;

  const size_t off_Xpad  = 0;          // 8*2042*768 bf16 = 25,092,096 B
  const size_t off_wdT   = 25092096;   // 768*768 bf16
  const size_t off_cwT   = 26271744;   // 2304*768 bf16
  const size_t off_Bblk  = 29810688;   // 3*36*16384 bf16 = 3,538,944 B
  const size_t off_bias2 = 33349632;   // 768 f32
  const size_t NEED      = 33352704;
  if (ws_size < NEED) return;

  char* ws = (char*)d_ws;
  unsigned short* Xpad  = (unsigned short*)(ws + off_Xpad);
  unsigned short* wdT   = (unsigned short*)(ws + off_wdT);
  unsigned short* cwT   = (unsigned short*)(ws + off_cwT);
  unsigned short* Bblk  = (unsigned short*)(ws + off_Bblk);
  float*          bias2 = (float*)(ws + off_bias2);

  k_pad<<<12252, 256, 0, stream>>>(X, Xpad);
  k_tr2<<<dim3(72, 24, 2), dim3(32, 8), 0, stream>>>(wd, wdT, conv_w, cwT);
  k_w2b<<<120, 256, 0, stream>>>(wdT, cwT, Bblk, conv_b, wd, bd, bias2);
  k_conv192<<<255, 512, 0, stream>>>(Xpad, Bblk, bias2, out);
}